// Round 9
// baseline (595.323 us; speedup 1.0000x reference)
//
#include <hip/hip_runtime.h>

// MOTCAT_Surv R9. KEY FIX: d_out is FP32 (reference output dtype is float32; the harness
// label hardcodes "bf16" misleadingly). All prior rounds wrote bf16 u16s into the fp32
// buffer -> half-covered, markers invisible, absmax pinned at max|ref|=3.734375.
// Conservative compute: all dense GEMMs are vanilla VALU fp32 (no MFMA, 8.7 KB LDS);
// MFMA only in bf16 screening; top-6 via fp64 rescore of 32 screened candidates.
// Dead-stage checkers write fp32 markers (1000/2000/3000/4000; 9000=ws guard) only if dead.

typedef __attribute__((ext_vector_type(8))) short short8;
typedef __attribute__((ext_vector_type(4))) short short4v;
typedef __attribute__((ext_vector_type(4))) float f32x4;

__device__ inline float bf2f(unsigned short b) {
    unsigned u = ((unsigned)b) << 16;
    return __builtin_bit_cast(float, u);
}
__device__ inline unsigned short f2bf(float f) {   // round-to-nearest-even
    unsigned u = __builtin_bit_cast(unsigned, f);
    unsigned r = u + 0x7fffu + ((u >> 16) & 1u);
    return (unsigned short)(r >> 16);
}
__device__ inline f32x4 mfma16(short8 a, short8 b, f32x4 c) {
    return __builtin_amdgcn_mfma_f32_16x16x32_bf16(a, b, c, 0, 0, 0);
}

// ---------------------------------------------------------------------------
// VALU fp32 GEMM: C[M,N] = act(A@B + bias) (+= old C if ACCUM). Tiles 64x64, BK=16.
// A fp32 (AISBF=0) or bf16 (AISBF=1). 256 thr; each computes 4x4. LDS 8,704 B.
// ---------------------------------------------------------------------------
template <int AISBF, int ACT, int ACCUM>
__launch_bounds__(256)
__global__ void gemmV(const void* __restrict__ Av, const float* __restrict__ B,
                      const float* __restrict__ bias, float* __restrict__ C,
                      int M, int N, int K) {
    __shared__ float As[64][17];
    __shared__ float Bs[16][68];
    const int t = threadIdx.x;
    const int row0 = blockIdx.y * 64, col0 = blockIdx.x * 64;
    const int tx = t & 15, ty = t >> 4;

    float acc[4][4];
    #pragma unroll
    for (int i = 0; i < 4; i++)
        #pragma unroll
        for (int j = 0; j < 4; j++) acc[i][j] = 0.0f;

    for (int kt = 0; kt < K; kt += 16) {
        {   // stage A: 64 rows x 16 k
            const int row = t >> 2, kq = (t & 3) * 4;
            if (AISBF) {
                const unsigned short* a16 = (const unsigned short*)Av;
                #pragma unroll
                for (int e = 0; e < 4; e++)
                    As[row][kq + e] = bf2f(a16[(size_t)(row0 + row) * K + kt + kq + e]);
            } else {
                const float* a32 = (const float*)Av;
                f32x4 v = *(const f32x4*)&a32[(size_t)(row0 + row) * K + kt + kq];
                #pragma unroll
                for (int e = 0; e < 4; e++) As[row][kq + e] = v[e];
            }
        }
        {   // stage B: 16 k x 64 n
            const int k = t >> 4, n4 = (t & 15) * 4;
            f32x4 v = *(const f32x4*)&B[(size_t)(kt + k) * N + col0 + n4];
            #pragma unroll
            for (int e = 0; e < 4; e++) Bs[k][n4 + e] = v[e];
        }
        __syncthreads();
        #pragma unroll
        for (int kk = 0; kk < 16; kk++) {
            float a0 = As[ty * 4 + 0][kk], a1 = As[ty * 4 + 1][kk];
            float a2 = As[ty * 4 + 2][kk], a3 = As[ty * 4 + 3][kk];
            float b0 = Bs[kk][tx * 4 + 0], b1 = Bs[kk][tx * 4 + 1];
            float b2 = Bs[kk][tx * 4 + 2], b3 = Bs[kk][tx * 4 + 3];
            acc[0][0] += a0 * b0; acc[0][1] += a0 * b1; acc[0][2] += a0 * b2; acc[0][3] += a0 * b3;
            acc[1][0] += a1 * b0; acc[1][1] += a1 * b1; acc[1][2] += a1 * b2; acc[1][3] += a1 * b3;
            acc[2][0] += a2 * b0; acc[2][1] += a2 * b1; acc[2][2] += a2 * b2; acc[2][3] += a2 * b3;
            acc[3][0] += a3 * b0; acc[3][1] += a3 * b1; acc[3][2] += a3 * b2; acc[3][3] += a3 * b3;
        }
        __syncthreads();
    }
    #pragma unroll
    for (int i = 0; i < 4; i++) {
        const int row = row0 + ty * 4 + i;
        #pragma unroll
        for (int j = 0; j < 4; j++) {
            const int col = col0 + tx * 4 + j;
            float v = acc[i][j] + bias[col];
            if (ACT == 1) v = v > 0.0f ? v : 0.01f * v;
            size_t idx = (size_t)row * N + col;
            if (ACCUM) v += C[idx];
            C[idx] = v;
        }
    }
}

// ---------------------------------------------------------------------------
__global__ void colsum_k(const float* __restrict__ x, float* __restrict__ out) {
    int d = threadIdx.x, b = blockIdx.x;
    float s = 0.0f;
    int i0 = b * 128;
    for (int i = 0; i < 128; i++) s += x[(size_t)(i0 + i) * 256 + d];
    out[b * 256 + d] = s;
}
__global__ void meanred_k(const float* __restrict__ p, float* __restrict__ mean) {
    int d = threadIdx.x;
    float s = 0.0f;
    for (int b = 0; b < 64; b++) s += p[b * 256 + d];
    mean[d] = s * (1.0f / 8192.0f);
}
__global__ void finalize_x(float* __restrict__ x, const float* __restrict__ mean) {
    size_t idx = (size_t)blockIdx.x * blockDim.x + threadIdx.x;
    f32x4 v = *(f32x4*)&x[idx * 4];
    int d4 = (int)((idx * 4) & 255);
    f32x4 m = *(const f32x4*)&mean[d4];
    #pragma unroll
    for (int e = 0; e < 4; e++) v[e] = (v[e] + m[e]) * 0.5f;
    *(f32x4*)&x[idx * 4] = v;
}
__global__ void f2bf_k(const float* __restrict__ src, unsigned short* __restrict__ dst, int n4) {
    size_t idx = (size_t)blockIdx.x * blockDim.x + threadIdx.x;
    if (idx >= (size_t)n4) return;
    f32x4 v = *(const f32x4*)&src[idx * 4];
    short4v h;
    #pragma unroll
    for (int e = 0; e < 4; e++) h[e] = (short)f2bf(v[e]);
    *(short4v*)&dst[idx * 4] = h;
}
__global__ void cpy_k(const float* __restrict__ src, float* __restrict__ dst) {
    size_t idx = (size_t)blockIdx.x * blockDim.x + threadIdx.x;
    *(f32x4*)&dst[idx * 4] = *(const f32x4*)&src[idx * 4];
}

// ---------------------------------------------------------------------------
// Screening: logits = e_h @ e_t^T (bf16 MFMA), top-8 per column quarter per row.
// Grid (4, 256 row-blocks of 32), 128 thr (2 waves). A-frags register-resident
// from global. LDS 10,624 B, phase-aliased.
// ---------------------------------------------------------------------------
template<int NK>
__device__ inline void insertN(float (&tv)[NK], int (&tj)[NK], float v, int j) {
    #pragma unroll
    for (int k = 0; k < NK; k++) {
        float nxt = (k < NK - 1) ? tv[k + 1] : 3.0e38f;
        int   nj  = (k < NK - 1) ? tj[k + 1] : 0;
        bool shift = (v > nxt);
        bool here  = !shift && (v > tv[k]);
        tv[k] = shift ? nxt : (here ? v : tv[k]);
        tj[k] = shift ? nj  : (here ? j : tj[k]);
    }
}

__launch_bounds__(128)
__global__ void screen_topk(const unsigned short* __restrict__ eh16,
                            const unsigned short* __restrict__ et16,
                            int* __restrict__ candi) {
    __shared__ __align__(16) char buf[10624];
    unsigned short* Bs = (unsigned short*)buf;
    float* scores = (float*)(buf + 8448);   // [32][17]
    float* mv = (float*)buf;                // merge: [32][32]
    int*   mj = (int*)(buf + 4096);
    const int t = threadIdx.x;
    const int cs = blockIdx.x;
    const int r0 = blockIdx.y * 32;
    const int w = t >> 6, lid = t & 63, g = lid >> 4, m16 = lid & 15;
    const int ar = w * 16;

    short8 afr[8];
    #pragma unroll
    for (int ks = 0; ks < 8; ks++)
        afr[ks] = *(const short8*)&eh16[(size_t)(r0 + ar + m16) * 256 + ks * 32 + g * 8];

    float tv[8]; int tj[8];
    #pragma unroll
    for (int q = 0; q < 8; q++) { tv[q] = -3.0e38f; tj[q] = 0; }
    const int srow = t >> 2, ssub = t & 3;

    for (int tile = 0; tile < 128; tile++) {
        const int j0 = cs * 2048 + tile * 16;
        {   // stage Bs: 16 cols x K=256
            int n = t >> 3, o = (t & 7) * 32;
            #pragma unroll
            for (int c = 0; c < 4; c++)
                *(short8*)&Bs[n * 264 + o + c * 8] =
                    *(const short8*)&et16[(size_t)(j0 + n) * 256 + o + c * 8];
        }
        __syncthreads();
        f32x4 a0 = {0.0f, 0.0f, 0.0f, 0.0f};
        #pragma unroll
        for (int ks = 0; ks < 8; ks++) {
            short8 b0 = *(const short8*)&Bs[m16 * 264 + ks * 32 + g * 8];
            a0 = mfma16(afr[ks], b0, a0);
        }
        #pragma unroll
        for (int r = 0; r < 4; r++)
            scores[(ar + g * 4 + r) * 17 + m16] = a0[r];
        __syncthreads();
        #pragma unroll
        for (int e = 0; e < 4; e++) {
            int col = ssub * 4 + e;
            float v = scores[srow * 17 + col];
            if (v > tv[0]) insertN<8>(tv, tj, v, j0 + col);
        }
    }
    __syncthreads();
    #pragma unroll
    for (int q = 0; q < 8; q++) {
        mv[srow * 32 + ssub * 8 + q] = tv[q];
        mj[srow * 32 + ssub * 8 + q] = tj[q];
    }
    __syncthreads();
    if (t < 32) {
        float fv[8]; int fj[8];
        #pragma unroll
        for (int q = 0; q < 8; q++) { fv[q] = -3.0e38f; fj[q] = 0; }
        for (int e = 0; e < 32; e++) {
            float v = mv[t * 32 + e];
            if (v > fv[0]) insertN<8>(fv, fj, v, mj[t * 32 + e]);
        }
        #pragma unroll
        for (int q = 0; q < 8; q++)
            candi[(size_t)(r0 + t) * 32 + cs * 8 + q] = fj[q];
    }
}

// ---------------------------------------------------------------------------
// Stage D: fp64 rescore of 32 candidates (shuffle-reduced), top-6 (tie: lower idx),
// softmax p, message, ka softmax, e_Nh -> m1 = bf16(e_h+e_Nh), m2 = bf16(e_h*e_Nh).
// One wave per row; lane l owns dims [4l,4l+4). Indices clamped. LDS ~3.6 KB.
// ---------------------------------------------------------------------------
__launch_bounds__(64)
__global__ void stageD(const float* __restrict__ eh, const float* __restrict__ et,
                       const int* __restrict__ candi,
                       unsigned short* __restrict__ m1, unsigned short* __restrict__ m2) {
    const int i = blockIdx.x, l = threadIdx.x;
    __shared__ int sj[32];
    __shared__ double slog[32];
    __shared__ float sred[64 * 12];
    __shared__ float ssum[12];
    __shared__ int selj[6];
    __shared__ float sp[6], skp[6];

    if (l < 32) sj[l] = candi[(size_t)i * 32 + l] & 8191;
    __syncthreads();
    f32x4 eh4 = *(const f32x4*)&eh[(size_t)i * 256 + l * 4];

    for (int c = 0; c < 32; c++) {
        const f32x4 t4 = *(const f32x4*)&et[(size_t)sj[c] * 256 + l * 4];
        double p = (double)eh4[0] * t4[0] + (double)eh4[1] * t4[1] +
                   (double)eh4[2] * t4[2] + (double)eh4[3] * t4[3];
        #pragma unroll
        for (int off = 1; off < 64; off <<= 1) p += __shfl_xor(p, off);
        if (l == 0) slog[c] = p * 0.0625;   // SCALE = 1/16
    }
    __syncthreads();
    if (l == 0) {
        unsigned used = 0;
        float w6[6];
        for (int s = 0; s < 6; s++) {
            double best = -1.0e300; int bj = 0x7fffffff, bc = 0;
            for (int c = 0; c < 32; c++) {
                if ((used >> c) & 1u) continue;
                double v = slog[c]; int j = sj[c];
                if (v > best || (v == best && j < bj)) { best = v; bj = j; bc = c; }
            }
            used |= 1u << bc;
            selj[s] = bj; w6[s] = (float)best;
        }
        float mx = w6[0];
        for (int s = 1; s < 6; s++) mx = fmaxf(mx, w6[s]);
        float se = 0.0f, e6[6];
        for (int s = 0; s < 6; s++) { e6[s] = expf(w6[s] - mx); se += e6[s]; }
        for (int s = 0; s < 6; s++) sp[s] = e6[s] / se;
    }
    __syncthreads();
    f32x4 nb[6];
    #pragma unroll
    for (int k = 0; k < 6; k++) nb[k] = *(const f32x4*)&et[(size_t)(selj[k] & 8191) * 256 + l * 4];
    #pragma unroll
    for (int k = 0; k < 6; k++) {
        float pk = sp[k];
        float pn = nb[k][0] + nb[k][1] + nb[k][2] + nb[k][3];
        float pg = 0.0f;
        #pragma unroll
        for (int e = 0; e < 4; e++) {
            float ehd = eh4[e], nbd = nb[k][e];
            float ehr = pk * nbd + (1.0f - pk) * ehd;
            pg += tanhf(ehd + ehr);
        }
        sred[l * 12 + k] = pn;
        sred[l * 12 + 6 + k] = pg;
    }
    __syncthreads();
    if (l < 12) {
        float s = 0.0f;
        for (int ll = 0; ll < 64; ll++) s += sred[ll * 12 + l];
        ssum[l] = s;
    }
    __syncthreads();
    if (l == 0) {
        float ka[6], mx = -3.0e38f, se = 0.0f;
        for (int k = 0; k < 6; k++) { ka[k] = ssum[k] * ssum[6 + k]; mx = fmaxf(mx, ka[k]); }
        for (int k = 0; k < 6; k++) { ka[k] = expf(ka[k] - mx); se += ka[k]; }
        for (int k = 0; k < 6; k++) skp[k] = ka[k] / se;
    }
    __syncthreads();
    f32x4 enh = {0.0f, 0.0f, 0.0f, 0.0f};
    #pragma unroll
    for (int k = 0; k < 6; k++) {
        float kp = skp[k];
        #pragma unroll
        for (int e = 0; e < 4; e++) enh[e] += kp * nb[k][e];
    }
    short4v h1, h2;
    #pragma unroll
    for (int e = 0; e < 4; e++) {
        h1[e] = (short)f2bf(eh4[e] + enh[e]);
        h2[e] = (short)f2bf(eh4[e] * enh[e]);
    }
    *(short4v*)&m1[(size_t)i * 256 + l * 4] = h1;
    *(short4v*)&m2[(size_t)i * 256 + l * 4] = h2;
}

// ---------------------------------------------------------------------------
// Readout (fp32 in/out)
// ---------------------------------------------------------------------------
__launch_bounds__(128)
__global__ void gate1_k(const float* __restrict__ emsg, const float* __restrict__ Ag1,
                        const float* __restrict__ bg1, const float* __restrict__ Ag2,
                        const float* __restrict__ bg2, float* __restrict__ glog) {
    const int i = blockIdx.x, h = threadIdx.x;
    __shared__ float em[256];
    __shared__ float red[128];
    em[h] = emsg[(size_t)i * 256 + h];
    em[h + 128] = emsg[(size_t)i * 256 + 128 + h];
    __syncthreads();
    float s = 0.0f;
    for (int d = 0; d < 256; d++) s += em[d] * Ag1[d * 128 + h];
    s += bg1[h];
    s = s > 0.0f ? s : 0.01f * s;
    red[h] = s * Ag2[h];
    __syncthreads();
    for (int st = 64; st > 0; st >>= 1) {
        if (h < st) red[h] += red[h + st];
        __syncthreads();
    }
    if (h == 0) glog[i] = red[0] + bg2[0];
}

__launch_bounds__(1024)
__global__ void softmax_g(const float* __restrict__ glog, float* __restrict__ gexp,
                          float* __restrict__ scal) {
    const int t = threadIdx.x;
    __shared__ float red[1024];
    float v[8];
    float m = -3.0e38f;
    #pragma unroll
    for (int c = 0; c < 8; c++) { v[c] = glog[t + c * 1024]; m = fmaxf(m, v[c]); }
    red[t] = m; __syncthreads();
    for (int st = 512; st > 0; st >>= 1) {
        if (t < st) red[t] = fmaxf(red[t], red[t + st]);
        __syncthreads();
    }
    float gm = red[0]; __syncthreads();
    float s = 0.0f;
    #pragma unroll
    for (int c = 0; c < 8; c++) {
        float e = expf(v[c] - gm);
        gexp[t + c * 1024] = e;
        s += e;
    }
    red[t] = s; __syncthreads();
    for (int st = 512; st > 0; st >>= 1) {
        if (t < st) red[t] += red[t + st];
        __syncthreads();
    }
    if (t == 0) scal[0] = 1.0f / red[0];
}

__launch_bounds__(256)
__global__ void wsum_k(const float* __restrict__ emsg, const float* __restrict__ gexp,
                       float* __restrict__ egp) {
    const int b = blockIdx.x, d = threadIdx.x;
    float s = 0.0f;
    const int i0 = b * 128;
    for (int i = 0; i < 128; i++) s += gexp[i0 + i] * emsg[(size_t)(i0 + i) * 256 + d];
    egp[b * 256 + d] = s;
}
__global__ void egfinal_f(const float* __restrict__ egp, const float* __restrict__ scal,
                          float* __restrict__ out) {
    const int d = threadIdx.x;
    float s = 0.0f;
    for (int b = 0; b < 64; b++) s += egp[b * 256 + d];
    out[d] = s * scal[0];
}

// ============================ DIAGNOSTICS (fp32-visible) ====================
__global__ void chk_f(const float* __restrict__ p, int i0, int i1, int i2, int i3,
                      float marker, float* __restrict__ out) {
    if (threadIdx.x != 0) return;
    float s = fabsf(p[i0]) + fabsf(p[i1]) + fabsf(p[i2]) + fabsf(p[i3]);
    if (s < 1.0e-6f) out[3] = marker;
}
__global__ void chk_b(const unsigned short* __restrict__ p, int i0, int i1, int i2, int i3,
                      float marker, float* __restrict__ out) {
    if (threadIdx.x != 0) return;
    float s = fabsf(bf2f(p[i0])) + fabsf(bf2f(p[i1])) + fabsf(bf2f(p[i2])) + fabsf(bf2f(p[i3]));
    if (s < 1.0e-6f) out[3] = marker;
}
__global__ void wsbad_k(float* __restrict__ out) { out[3] = 9000.0f; }

// ---------------------------------------------------------------------------
extern "C" void kernel_launch(void* const* d_in, const int* in_sizes, int n_in,
                              void* d_out, int out_size, void* d_ws, size_t ws_size,
                              hipStream_t stream) {
    (void)in_sizes; (void)n_in; (void)out_size;
    const float* x_path = (const float*)d_in[0];
    const float* fc1_W  = (const float*)d_in[1];
    const float* fc1_b  = (const float*)d_in[2];
    const float* Wh     = (const float*)d_in[3];
    const float* bh     = (const float*)d_in[4];
    const float* Wt     = (const float*)d_in[5];
    const float* bt     = (const float*)d_in[6];
    const float* W1     = (const float*)d_in[7];
    const float* b1     = (const float*)d_in[8];
    const float* W2     = (const float*)d_in[9];
    const float* b2     = (const float*)d_in[10];
    const float* Ag1    = (const float*)d_in[11];
    const float* bg1    = (const float*)d_in[12];
    const float* Ag2    = (const float*)d_in[13];
    const float* bg2    = (const float*)d_in[14];
    float* out_f = (float*)d_out;   // FP32 output: e_msg [0,2097152), e_g [2097152,2097408)

    // ws (26.42 MB <= 26.67 MB proven available in R3):
    //   A [0,8M):    x fp32 -> eh16[0,4M)+et16[4M,8M) -> m1b[0,4M)+m2b[4M,8M)
    //   B [8M,16M):  eh fp32 -> emsg fp32
    //   C [16M,24M): et fp32
    //   D tail: candi, meanp, meanv, glog, gexp, egp, scal
    const size_t WS_NEEDED = 26412048;
    if (ws_size < WS_NEEDED) {
        hipLaunchKernelGGL(wsbad_k, dim3(1), dim3(1), 0, stream, out_f);
        return;
    }

    char* ws = (char*)d_ws;
    float* x     = (float*)(ws + 0);
    unsigned short* eh16 = (unsigned short*)(ws + 0);
    unsigned short* et16 = (unsigned short*)(ws + 4194304);
    unsigned short* m1b  = (unsigned short*)(ws + 0);
    unsigned short* m2b  = (unsigned short*)(ws + 4194304);
    float* eh    = (float*)(ws + 8388608);
    float* emsg  = (float*)(ws + 8388608);
    float* et    = (float*)(ws + 16777216);
    int*   candi = (int*)  (ws + 25165824);
    float* meanp = (float*)(ws + 26214400);
    float* meanv = (float*)(ws + 26279936);
    float* glog  = (float*)(ws + 26280960);
    float* gexp  = (float*)(ws + 26313728);
    float* egp   = (float*)(ws + 26346496);
    float* scal  = (float*)(ws + 26412032);

    dim3 gg(4, 128);   // 256/64 x 8192/64
    // 1) x = leaky(x_path @ fc1_W + fc1_b)
    hipLaunchKernelGGL((gemmV<0, 1, 0>), gg, dim3(256), 0, stream,
                       (const void*)x_path, fc1_W, fc1_b, x, 8192, 256, 1024);
    // 2) x = (x + mean(x)) * 0.5
    hipLaunchKernelGGL(colsum_k, dim3(64), dim3(256), 0, stream, x, meanp);
    hipLaunchKernelGGL(meanred_k, dim3(1), dim3(256), 0, stream, meanp, meanv);
    hipLaunchKernelGGL(finalize_x, dim3(2048), dim3(256), 0, stream, x, meanv);
    // 3) e_h, e_t (fp32 exact)
    hipLaunchKernelGGL((gemmV<0, 0, 0>), gg, dim3(256), 0, stream,
                       (const void*)x, Wh, bh, eh, 8192, 256, 256);
    hipLaunchKernelGGL((gemmV<0, 0, 0>), gg, dim3(256), 0, stream,
                       (const void*)x, Wt, bt, et, 8192, 256, 256);
    // 4) bf16 copies for screening (x dead -> region A)
    hipLaunchKernelGGL(f2bf_k, dim3(2048), dim3(256), 0, stream, eh, eh16, 524288);
    hipLaunchKernelGGL(f2bf_k, dim3(2048), dim3(256), 0, stream, et, et16, 524288);
    // 5) screening: top-8 per quarter -> 32 candidates/row
    hipLaunchKernelGGL(screen_topk, dim3(4, 256), dim3(128), 0, stream, eh16, et16, candi);
    // 6) fp64 select + message -> m1b/m2b bf16 (overwrite eh16/et16)
    hipLaunchKernelGGL(stageD, dim3(8192), dim3(64), 0, stream, eh, et, candi, m1b, m2b);
    // 7) e_msg = leaky(m1@W1+b1) + leaky(m2@W2+b2)   (emsg overwrites dead eh)
    hipLaunchKernelGGL((gemmV<1, 1, 0>), gg, dim3(256), 0, stream,
                       (const void*)m1b, W1, b1, emsg, 8192, 256, 256);
    hipLaunchKernelGGL((gemmV<1, 1, 1>), gg, dim3(256), 0, stream,
                       (const void*)m2b, W2, b2, emsg, 8192, 256, 256);
    // 8) output 0: e_msg fp32
    hipLaunchKernelGGL(cpy_k, dim3(2048), dim3(256), 0, stream, emsg, out_f);
    // 9) readout -> output 1: e_g fp32
    hipLaunchKernelGGL(gate1_k, dim3(8192), dim3(128), 0, stream, emsg, Ag1, bg1, Ag2, bg2, glog);
    hipLaunchKernelGGL(softmax_g, dim3(1), dim3(1024), 0, stream, glog, gexp, scal);
    hipLaunchKernelGGL(wsum_k, dim3(64), dim3(256), 0, stream, emsg, gexp, egp);
    hipLaunchKernelGGL(egfinal_f, dim3(1), dim3(256), 0, stream, egp, scal, out_f + 2097152);
    // 10) dead-stage checkers (write out_f[3] only if dead; latest write = earliest stage)
    hipLaunchKernelGGL(chk_f, dim3(1), dim3(64), 0, stream,
                       emsg, 3, 200000, 1000003, 1500000, 4000.0f, out_f);
    hipLaunchKernelGGL(chk_b, dim3(1), dim3(64), 0, stream,
                       m1b, 100, 50000, 999999, 1999999, 3000.0f, out_f);
    hipLaunchKernelGGL(chk_f, dim3(1), dim3(64), 0, stream,
                       et, 1000, 500000, 1000000, 2000000, 2000.0f, out_f);
    hipLaunchKernelGGL(chk_f, dim3(1), dim3(64), 0, stream,
                       meanv, 0, 50, 100, 200, 1000.0f, out_f);
}

// Round 10
// 554.382 us; speedup vs baseline: 1.0739x; 1.0739x over previous
//
#include <hip/hip_runtime.h>

// MOTCAT_Surv R10. R9 passed (absmax 0.0156, 595 us). This round: kill the screen_topk
// whale (207 us, MfmaUtil 6.6%) via register-resident top-k (no scores LDS round-trip,
// shuffle-butterfly merge) + 64-row blocks; split gate1_k's 1 GB L2 re-read into a
// gemmV (8192x128) + small dot kernel. Everything else identical to the proven R9.

typedef __attribute__((ext_vector_type(8))) short short8;
typedef __attribute__((ext_vector_type(4))) short short4v;
typedef __attribute__((ext_vector_type(4))) float f32x4;

__device__ inline float bf2f(unsigned short b) {
    unsigned u = ((unsigned)b) << 16;
    return __builtin_bit_cast(float, u);
}
__device__ inline unsigned short f2bf(float f) {   // round-to-nearest-even
    unsigned u = __builtin_bit_cast(unsigned, f);
    unsigned r = u + 0x7fffu + ((u >> 16) & 1u);
    return (unsigned short)(r >> 16);
}
__device__ inline f32x4 mfma16(short8 a, short8 b, f32x4 c) {
    return __builtin_amdgcn_mfma_f32_16x16x32_bf16(a, b, c, 0, 0, 0);
}
// A-frag: lane holds A[m=lane&15][k=(lane>>4)*8+j]; B-frag: B[k][n=lane&15];
// C/D: col=lane&15, row=(lane>>4)*4+reg (learn_hip m89).

// ---------------------------------------------------------------------------
// VALU fp32 GEMM (proven R9): C = act(A@B + bias) (+=C if ACCUM). 64x64 tile, BK=16.
// ---------------------------------------------------------------------------
template <int AISBF, int ACT, int ACCUM>
__launch_bounds__(256)
__global__ void gemmV(const void* __restrict__ Av, const float* __restrict__ B,
                      const float* __restrict__ bias, float* __restrict__ C,
                      int M, int N, int K) {
    __shared__ float As[64][17];
    __shared__ float Bs[16][68];
    const int t = threadIdx.x;
    const int row0 = blockIdx.y * 64, col0 = blockIdx.x * 64;
    const int tx = t & 15, ty = t >> 4;

    float acc[4][4];
    #pragma unroll
    for (int i = 0; i < 4; i++)
        #pragma unroll
        for (int j = 0; j < 4; j++) acc[i][j] = 0.0f;

    for (int kt = 0; kt < K; kt += 16) {
        {
            const int row = t >> 2, kq = (t & 3) * 4;
            if (AISBF) {
                const unsigned short* a16 = (const unsigned short*)Av;
                #pragma unroll
                for (int e = 0; e < 4; e++)
                    As[row][kq + e] = bf2f(a16[(size_t)(row0 + row) * K + kt + kq + e]);
            } else {
                const float* a32 = (const float*)Av;
                f32x4 v = *(const f32x4*)&a32[(size_t)(row0 + row) * K + kt + kq];
                #pragma unroll
                for (int e = 0; e < 4; e++) As[row][kq + e] = v[e];
            }
        }
        {
            const int k = t >> 4, n4 = (t & 15) * 4;
            f32x4 v = *(const f32x4*)&B[(size_t)(kt + k) * N + col0 + n4];
            #pragma unroll
            for (int e = 0; e < 4; e++) Bs[k][n4 + e] = v[e];
        }
        __syncthreads();
        #pragma unroll
        for (int kk = 0; kk < 16; kk++) {
            float a0 = As[ty * 4 + 0][kk], a1 = As[ty * 4 + 1][kk];
            float a2 = As[ty * 4 + 2][kk], a3 = As[ty * 4 + 3][kk];
            float b0 = Bs[kk][tx * 4 + 0], b1 = Bs[kk][tx * 4 + 1];
            float b2 = Bs[kk][tx * 4 + 2], b3 = Bs[kk][tx * 4 + 3];
            acc[0][0] += a0 * b0; acc[0][1] += a0 * b1; acc[0][2] += a0 * b2; acc[0][3] += a0 * b3;
            acc[1][0] += a1 * b0; acc[1][1] += a1 * b1; acc[1][2] += a1 * b2; acc[1][3] += a1 * b3;
            acc[2][0] += a2 * b0; acc[2][1] += a2 * b1; acc[2][2] += a2 * b2; acc[2][3] += a2 * b3;
            acc[3][0] += a3 * b0; acc[3][1] += a3 * b1; acc[3][2] += a3 * b2; acc[3][3] += a3 * b3;
        }
        __syncthreads();
    }
    #pragma unroll
    for (int i = 0; i < 4; i++) {
        const int row = row0 + ty * 4 + i;
        #pragma unroll
        for (int j = 0; j < 4; j++) {
            const int col = col0 + tx * 4 + j;
            float v = acc[i][j] + bias[col];
            if (ACT == 1) v = v > 0.0f ? v : 0.01f * v;
            size_t idx = (size_t)row * N + col;
            if (ACCUM) v += C[idx];
            C[idx] = v;
        }
    }
}

// ---------------------------------------------------------------------------
__global__ void colsum_k(const float* __restrict__ x, float* __restrict__ out) {
    int d = threadIdx.x, b = blockIdx.x;
    float s = 0.0f;
    int i0 = b * 128;
    for (int i = 0; i < 128; i++) s += x[(size_t)(i0 + i) * 256 + d];
    out[b * 256 + d] = s;
}
__global__ void meanred_k(const float* __restrict__ p, float* __restrict__ mean) {
    int d = threadIdx.x;
    float s = 0.0f;
    for (int b = 0; b < 64; b++) s += p[b * 256 + d];
    mean[d] = s * (1.0f / 8192.0f);
}
__global__ void finalize_x(float* __restrict__ x, const float* __restrict__ mean) {
    size_t idx = (size_t)blockIdx.x * blockDim.x + threadIdx.x;
    f32x4 v = *(f32x4*)&x[idx * 4];
    int d4 = (int)((idx * 4) & 255);
    f32x4 m = *(const f32x4*)&mean[d4];
    #pragma unroll
    for (int e = 0; e < 4; e++) v[e] = (v[e] + m[e]) * 0.5f;
    *(f32x4*)&x[idx * 4] = v;
}
__global__ void f2bf_k(const float* __restrict__ src, unsigned short* __restrict__ dst, int n4) {
    size_t idx = (size_t)blockIdx.x * blockDim.x + threadIdx.x;
    if (idx >= (size_t)n4) return;
    f32x4 v = *(const f32x4*)&src[idx * 4];
    short4v h;
    #pragma unroll
    for (int e = 0; e < 4; e++) h[e] = (short)f2bf(v[e]);
    *(short4v*)&dst[idx * 4] = h;
}
__global__ void cpy_k(const float* __restrict__ src, float* __restrict__ dst) {
    size_t idx = (size_t)blockIdx.x * blockDim.x + threadIdx.x;
    *(f32x4*)&dst[idx * 4] = *(const f32x4*)&src[idx * 4];
}

// ---------------------------------------------------------------------------
template<int NK>
__device__ inline void insertN(float (&tv)[NK], int (&tj)[NK], float v, int j) {
    #pragma unroll
    for (int k = 0; k < NK; k++) {
        float nxt = (k < NK - 1) ? tv[k + 1] : 3.0e38f;
        int   nj  = (k < NK - 1) ? tj[k + 1] : 0;
        bool shift = (v > nxt);
        bool here  = !shift && (v > tv[k]);
        tv[k] = shift ? nxt : (here ? v : tv[k]);
        tj[k] = shift ? nj  : (here ? j : tj[k]);
    }
}

// ---------------------------------------------------------------------------
// screen2: logits = e_h @ e_t^T (bf16 MFMA), top-8 per column quarter per row.
// Grid (4 quarters, 128 row-blocks of 64); 256 thr = 4 waves x 16 rows.
// A-frags register-resident; B tile (32 cols x K=256) in LDS (16,896 B);
// top-8 per (lane,row) in REGISTERS (cols == m16 mod 16 slice => slice top-8
// superset of slice top-6 => merged top-8/quarter superset of true top-6);
// merge across the 16 col-slice lanes via shfl_xor butterfly (snapshot-then-insert).
// ---------------------------------------------------------------------------
__launch_bounds__(256)
__global__ void screen2(const unsigned short* __restrict__ eh16,
                        const unsigned short* __restrict__ et16,
                        int* __restrict__ candi) {
    __shared__ __align__(16) unsigned short Bs[32][264];
    const int t = threadIdx.x;
    const int cs = blockIdx.x;
    const int r0 = blockIdx.y * 64;
    const int w = t >> 6, lid = t & 63, g = lid >> 4, m16 = lid & 15;
    const int ar = w * 16;

    short8 afr[8];   // this wave's 16 rows, K=256
    #pragma unroll
    for (int ks = 0; ks < 8; ks++)
        afr[ks] = *(const short8*)&eh16[(size_t)(r0 + ar + m16) * 256 + ks * 32 + g * 8];

    float tv[4][8]; int tj[4][8];
    #pragma unroll
    for (int r = 0; r < 4; r++)
        #pragma unroll
        for (int q = 0; q < 8; q++) { tv[r][q] = -3.0e38f; tj[r][q] = 0; }

    for (int tile = 0; tile < 64; tile++) {
        const int j0 = cs * 2048 + tile * 32;
        {   // stage 32 cols x 256 k
            int n = t >> 3, o = (t & 7) * 32;
            #pragma unroll
            for (int c = 0; c < 4; c++)
                *(short8*)&Bs[n][o + c * 8] =
                    *(const short8*)&et16[(size_t)(j0 + n) * 256 + o + c * 8];
        }
        __syncthreads();
        f32x4 a0 = {0.0f, 0.0f, 0.0f, 0.0f}, a1 = a0;
        #pragma unroll
        for (int ks = 0; ks < 8; ks++) {
            short8 b0 = *(const short8*)&Bs[m16][ks * 32 + g * 8];
            short8 b1 = *(const short8*)&Bs[16 + m16][ks * 32 + g * 8];
            a0 = mfma16(afr[ks], b0, a0);
            a1 = mfma16(afr[ks], b1, a1);
        }
        __syncthreads();   // all LDS reads done before next staging overwrites Bs
        #pragma unroll
        for (int r = 0; r < 4; r++) {
            float v0 = a0[r];
            if (v0 > tv[r][0]) insertN<8>(tv[r], tj[r], v0, j0 + m16);
            float v1 = a1[r];
            if (v1 > tv[r][0]) insertN<8>(tv[r], tj[r], v1, j0 + 16 + m16);
        }
    }
    // butterfly merge across the 16 lanes (same g group) sharing each row
    #pragma unroll
    for (int step = 1; step < 16; step <<= 1) {
        #pragma unroll
        for (int r = 0; r < 4; r++) {
            float ov[8]; int oj[8];
            #pragma unroll
            for (int q = 0; q < 8; q++) {
                ov[q] = __shfl_xor(tv[r][q], step);
                oj[q] = __shfl_xor(tj[r][q], step);
            }
            #pragma unroll
            for (int q = 0; q < 8; q++)
                if (ov[q] > tv[r][0]) insertN<8>(tv[r], tj[r], ov[q], oj[q]);
        }
    }
    if (m16 == 0) {
        #pragma unroll
        for (int r = 0; r < 4; r++) {
            const int row = r0 + ar + g * 4 + r;
            #pragma unroll
            for (int q = 0; q < 8; q++)
                candi[(size_t)row * 32 + cs * 8 + q] = tj[r][q];
        }
    }
}

// ---------------------------------------------------------------------------
// Stage D (proven R9): fp64 rescore of 32 candidates, top-6, softmax p, message,
// ka softmax, e_Nh -> m1/m2 bf16. One wave per row.
// ---------------------------------------------------------------------------
__launch_bounds__(64)
__global__ void stageD(const float* __restrict__ eh, const float* __restrict__ et,
                       const int* __restrict__ candi,
                       unsigned short* __restrict__ m1, unsigned short* __restrict__ m2) {
    const int i = blockIdx.x, l = threadIdx.x;
    __shared__ int sj[32];
    __shared__ double slog[32];
    __shared__ float sred[64 * 12];
    __shared__ float ssum[12];
    __shared__ int selj[6];
    __shared__ float sp[6], skp[6];

    if (l < 32) sj[l] = candi[(size_t)i * 32 + l] & 8191;
    __syncthreads();
    f32x4 eh4 = *(const f32x4*)&eh[(size_t)i * 256 + l * 4];

    for (int c = 0; c < 32; c++) {
        const f32x4 t4 = *(const f32x4*)&et[(size_t)sj[c] * 256 + l * 4];
        double p = (double)eh4[0] * t4[0] + (double)eh4[1] * t4[1] +
                   (double)eh4[2] * t4[2] + (double)eh4[3] * t4[3];
        #pragma unroll
        for (int off = 1; off < 64; off <<= 1) p += __shfl_xor(p, off);
        if (l == 0) slog[c] = p * 0.0625;
    }
    __syncthreads();
    if (l == 0) {
        unsigned used = 0;
        float w6[6];
        for (int s = 0; s < 6; s++) {
            double best = -1.0e300; int bj = 0x7fffffff, bc = 0;
            for (int c = 0; c < 32; c++) {
                if ((used >> c) & 1u) continue;
                double v = slog[c]; int j = sj[c];
                if (v > best || (v == best && j < bj)) { best = v; bj = j; bc = c; }
            }
            used |= 1u << bc;
            selj[s] = bj; w6[s] = (float)best;
        }
        float mx = w6[0];
        for (int s = 1; s < 6; s++) mx = fmaxf(mx, w6[s]);
        float se = 0.0f, e6[6];
        for (int s = 0; s < 6; s++) { e6[s] = expf(w6[s] - mx); se += e6[s]; }
        for (int s = 0; s < 6; s++) sp[s] = e6[s] / se;
    }
    __syncthreads();
    f32x4 nb[6];
    #pragma unroll
    for (int k = 0; k < 6; k++) nb[k] = *(const f32x4*)&et[(size_t)(selj[k] & 8191) * 256 + l * 4];
    #pragma unroll
    for (int k = 0; k < 6; k++) {
        float pk = sp[k];
        float pn = nb[k][0] + nb[k][1] + nb[k][2] + nb[k][3];
        float pg = 0.0f;
        #pragma unroll
        for (int e = 0; e < 4; e++) {
            float ehd = eh4[e], nbd = nb[k][e];
            float ehr = pk * nbd + (1.0f - pk) * ehd;
            pg += tanhf(ehd + ehr);
        }
        sred[l * 12 + k] = pn;
        sred[l * 12 + 6 + k] = pg;
    }
    __syncthreads();
    if (l < 12) {
        float s = 0.0f;
        for (int ll = 0; ll < 64; ll++) s += sred[ll * 12 + l];
        ssum[l] = s;
    }
    __syncthreads();
    if (l == 0) {
        float ka[6], mx = -3.0e38f, se = 0.0f;
        for (int k = 0; k < 6; k++) { ka[k] = ssum[k] * ssum[6 + k]; mx = fmaxf(mx, ka[k]); }
        for (int k = 0; k < 6; k++) { ka[k] = expf(ka[k] - mx); se += ka[k]; }
        for (int k = 0; k < 6; k++) skp[k] = ka[k] / se;
    }
    __syncthreads();
    f32x4 enh = {0.0f, 0.0f, 0.0f, 0.0f};
    #pragma unroll
    for (int k = 0; k < 6; k++) {
        float kp = skp[k];
        #pragma unroll
        for (int e = 0; e < 4; e++) enh[e] += kp * nb[k][e];
    }
    short4v h1, h2;
    #pragma unroll
    for (int e = 0; e < 4; e++) {
        h1[e] = (short)f2bf(eh4[e] + enh[e]);
        h2[e] = (short)f2bf(eh4[e] * enh[e]);
    }
    *(short4v*)&m1[(size_t)i * 256 + l * 4] = h1;
    *(short4v*)&m2[(size_t)i * 256 + l * 4] = h2;
}

// ---------------------------------------------------------------------------
// Readout: g1 = leaky(emsg@Ag1+bg1) via gemmV; then glog = g1@Ag2 + bg2.
// ---------------------------------------------------------------------------
__launch_bounds__(256)
__global__ void gate2_k(const float* __restrict__ g1, const float* __restrict__ Ag2,
                        const float* __restrict__ bg2, float* __restrict__ glog) {
    const int i = blockIdx.x * 256 + threadIdx.x;
    float s = 0.0f;
    #pragma unroll 4
    for (int h = 0; h < 128; h++) s += g1[(size_t)i * 128 + h] * Ag2[h];
    glog[i] = s + bg2[0];
}

__launch_bounds__(1024)
__global__ void softmax_g(const float* __restrict__ glog, float* __restrict__ gexp,
                          float* __restrict__ scal) {
    const int t = threadIdx.x;
    __shared__ float red[1024];
    float v[8];
    float m = -3.0e38f;
    #pragma unroll
    for (int c = 0; c < 8; c++) { v[c] = glog[t + c * 1024]; m = fmaxf(m, v[c]); }
    red[t] = m; __syncthreads();
    for (int st = 512; st > 0; st >>= 1) {
        if (t < st) red[t] = fmaxf(red[t], red[t + st]);
        __syncthreads();
    }
    float gm = red[0]; __syncthreads();
    float s = 0.0f;
    #pragma unroll
    for (int c = 0; c < 8; c++) {
        float e = expf(v[c] - gm);
        gexp[t + c * 1024] = e;
        s += e;
    }
    red[t] = s; __syncthreads();
    for (int st = 512; st > 0; st >>= 1) {
        if (t < st) red[t] += red[t + st];
        __syncthreads();
    }
    if (t == 0) scal[0] = 1.0f / red[0];
}

__launch_bounds__(256)
__global__ void wsum_k(const float* __restrict__ emsg, const float* __restrict__ gexp,
                       float* __restrict__ egp) {
    const int b = blockIdx.x, d = threadIdx.x;
    float s = 0.0f;
    const int i0 = b * 128;
    for (int i = 0; i < 128; i++) s += gexp[i0 + i] * emsg[(size_t)(i0 + i) * 256 + d];
    egp[b * 256 + d] = s;
}
__global__ void egfinal_f(const float* __restrict__ egp, const float* __restrict__ scal,
                          float* __restrict__ out) {
    const int d = threadIdx.x;
    float s = 0.0f;
    for (int b = 0; b < 64; b++) s += egp[b * 256 + d];
    out[d] = s * scal[0];
}

__global__ void wsbad_k(float* __restrict__ out) { out[3] = 9000.0f; }

// ---------------------------------------------------------------------------
extern "C" void kernel_launch(void* const* d_in, const int* in_sizes, int n_in,
                              void* d_out, int out_size, void* d_ws, size_t ws_size,
                              hipStream_t stream) {
    (void)in_sizes; (void)n_in; (void)out_size;
    const float* x_path = (const float*)d_in[0];
    const float* fc1_W  = (const float*)d_in[1];
    const float* fc1_b  = (const float*)d_in[2];
    const float* Wh     = (const float*)d_in[3];
    const float* bh     = (const float*)d_in[4];
    const float* Wt     = (const float*)d_in[5];
    const float* bt     = (const float*)d_in[6];
    const float* W1     = (const float*)d_in[7];
    const float* b1     = (const float*)d_in[8];
    const float* W2     = (const float*)d_in[9];
    const float* b2     = (const float*)d_in[10];
    const float* Ag1    = (const float*)d_in[11];
    const float* bg1    = (const float*)d_in[12];
    const float* Ag2    = (const float*)d_in[13];
    const float* bg2    = (const float*)d_in[14];
    float* out_f = (float*)d_out;   // fp32: e_msg [0,2097152), e_g [2097152,2097408)

    const size_t WS_NEEDED = 26412048;
    if (ws_size < WS_NEEDED) {
        hipLaunchKernelGGL(wsbad_k, dim3(1), dim3(1), 0, stream, out_f);
        return;
    }

    char* ws = (char*)d_ws;
    float* x     = (float*)(ws + 0);
    unsigned short* eh16 = (unsigned short*)(ws + 0);
    unsigned short* et16 = (unsigned short*)(ws + 4194304);
    unsigned short* m1b  = (unsigned short*)(ws + 0);
    unsigned short* m2b  = (unsigned short*)(ws + 4194304);
    float* g1    = (float*)(ws + 0);          // 8192x128 fp32 (after m1b/m2b dead)
    float* eh    = (float*)(ws + 8388608);
    float* emsg  = (float*)(ws + 8388608);
    float* et    = (float*)(ws + 16777216);
    int*   candi = (int*)  (ws + 25165824);
    float* meanp = (float*)(ws + 26214400);
    float* meanv = (float*)(ws + 26279936);
    float* glog  = (float*)(ws + 26280960);
    float* gexp  = (float*)(ws + 26313728);
    float* egp   = (float*)(ws + 26346496);
    float* scal  = (float*)(ws + 26412032);

    dim3 gg(4, 128);
    // 1) x = leaky(x_path @ fc1_W + fc1_b)
    hipLaunchKernelGGL((gemmV<0, 1, 0>), gg, dim3(256), 0, stream,
                       (const void*)x_path, fc1_W, fc1_b, x, 8192, 256, 1024);
    // 2) x = (x + mean(x)) * 0.5
    hipLaunchKernelGGL(colsum_k, dim3(64), dim3(256), 0, stream, x, meanp);
    hipLaunchKernelGGL(meanred_k, dim3(1), dim3(256), 0, stream, meanp, meanv);
    hipLaunchKernelGGL(finalize_x, dim3(2048), dim3(256), 0, stream, x, meanv);
    // 3) e_h, e_t (fp32 exact)
    hipLaunchKernelGGL((gemmV<0, 0, 0>), gg, dim3(256), 0, stream,
                       (const void*)x, Wh, bh, eh, 8192, 256, 256);
    hipLaunchKernelGGL((gemmV<0, 0, 0>), gg, dim3(256), 0, stream,
                       (const void*)x, Wt, bt, et, 8192, 256, 256);
    // 4) bf16 copies for screening
    hipLaunchKernelGGL(f2bf_k, dim3(2048), dim3(256), 0, stream, eh, eh16, 524288);
    hipLaunchKernelGGL(f2bf_k, dim3(2048), dim3(256), 0, stream, et, et16, 524288);
    // 5) screening: register top-8 per quarter -> 32 candidates/row
    hipLaunchKernelGGL(screen2, dim3(4, 128), dim3(256), 0, stream, eh16, et16, candi);
    // 6) fp64 select + message -> m1b/m2b
    hipLaunchKernelGGL(stageD, dim3(8192), dim3(64), 0, stream, eh, et, candi, m1b, m2b);
    // 7) e_msg = leaky(m1@W1+b1) + leaky(m2@W2+b2)
    hipLaunchKernelGGL((gemmV<1, 1, 0>), gg, dim3(256), 0, stream,
                       (const void*)m1b, W1, b1, emsg, 8192, 256, 256);
    hipLaunchKernelGGL((gemmV<1, 1, 1>), gg, dim3(256), 0, stream,
                       (const void*)m2b, W2, b2, emsg, 8192, 256, 256);
    // 8) output 0: e_msg fp32
    hipLaunchKernelGGL(cpy_k, dim3(2048), dim3(256), 0, stream, emsg, out_f);
    // 9) readout: g1 = leaky(emsg@Ag1+bg1); glog = g1@Ag2+bg2; softmax; weighted sum
    hipLaunchKernelGGL((gemmV<0, 1, 0>), dim3(2, 128), dim3(256), 0, stream,
                       (const void*)emsg, Ag1, bg1, g1, 8192, 128, 256);
    hipLaunchKernelGGL(gate2_k, dim3(32), dim3(256), 0, stream, g1, Ag2, bg2, glog);
    hipLaunchKernelGGL(softmax_g, dim3(1), dim3(1024), 0, stream, glog, gexp, scal);
    hipLaunchKernelGGL(wsum_k, dim3(64), dim3(256), 0, stream, emsg, gexp, egp);
    hipLaunchKernelGGL(egfinal_f, dim3(1), dim3(256), 0, stream, egp, scal, out_f + 2097152);
}